// Round 8
// baseline (201.595 us; speedup 1.0000x reference)
//
#include <hip/hip_runtime.h>

// 14-qubit state-vector sim, one workgroup per batch element, state in LDS.
// Wire w <-> bit (13-w). CNOT rings folded into scatter writes.
// R8: 1024 thr x 16 amps, wave-local stages. Amp bits[13:10] = wave id.
//     Stage A: gates on bits 0-3 (wires 13..10), contiguous b128.
//     Stage B: gates on bits 4-7 (wires 9..6), wave-local transpose.
//     Stage C: gates on bits 8-9 (wires 5,4), wave-local.
//     Stage D: gates on bits 10-13 (wires 3..0) + ring scatter, cross-wave.
//     A->B->C need only s_waitcnt lgkmcnt(0) (wave lockstep, disjoint wave
//     regions); only D needs __syncthreads (3/layer vs R7's 4).

#define NW 14
#define NSTATE (1 << NW)                      // 16384
#define NTHREADS 1024
#define STATE_SLOTS (NSTATE + ((NSTATE >> 6) << 1))   // 16896 float2

typedef float v2f __attribute__((ext_vector_type(2)));

__device__ __forceinline__ float2 cmul(float2 a, float2 b) {
    return make_float2(a.x * b.x - a.y * b.y, a.x * b.y + a.y * b.x);
}
__device__ __forceinline__ void wavewait() {
    asm volatile("s_waitcnt lgkmcnt(0)" ::: "memory");
}

// ---- VOP3P packed helpers (R5-verified semantics) ----
__device__ __forceinline__ v2f pk_mul_bl(v2f a, v2f b) {   // {a.lo*b.lo, a.hi*b.lo}
    v2f d; asm("v_pk_mul_f32 %0, %1, %2 op_sel:[0,0] op_sel_hi:[1,0]"
               : "=v"(d) : "v"(a), "v"(b)); return d;
}
__device__ __forceinline__ v2f pk_fma_bl(v2f a, v2f b, v2f c) {
    v2f d; asm("v_pk_fma_f32 %0, %1, %2, %3 op_sel:[0,0,0] op_sel_hi:[1,0,1]"
               : "=v"(d) : "v"(a), "v"(b), "v"(c)); return d;
}
__device__ __forceinline__ v2f pk_fma_sw(v2f a, v2f b, v2f c) { // {a.hi*b.lo+c.lo, a.lo*b.hi+c.hi}
    v2f d; asm("v_pk_fma_f32 %0, %1, %2, %3 op_sel:[1,0,0] op_sel_hi:[0,1,1]"
               : "=v"(d) : "v"(a), "v"(b), "v"(c)); return d;
}

// ---- compile-time CNOT-ring constants ----
struct RingConsts { unsigned col[2][NW]; unsigned flowD[2][16]; };
constexpr RingConsts make_rc() {
    RingConsts rc{};
    for (int ri = 0; ri < 2; ++ri) {
        for (int bb = 0; bb < NW; ++bb) {
            unsigned x = 1u << bb;
            for (int w = 0; w < NW; ++w) {
                int pc = 13 - w, pt = 13 - ((w + ri + 1) % NW);
                x ^= ((x >> pc) & 1u) << pt;
            }
            rc.col[ri][bb] = x;
        }
        for (int k = 0; k < 16; ++k) {          // image of amp bits 10..13
            unsigned x = 0;
            for (int j = 0; j < 4; ++j) if ((k >> j) & 1) x ^= rc.col[ri][10 + j];
            rc.flowD[ri][k] = x;
        }
    }
    return rc;
}
constexpr RingConsts RC = make_rc();

// Gate consts per wire W (4 float4 per gate: {u.re, u.im, -u.im, +u.im})
#define GSTAGE(W) \
    const float4 g0 = G4[(W)*4+0], g1 = G4[(W)*4+1], \
                 g2 = G4[(W)*4+2], g3 = G4[(W)*4+3]; \
    const v2f U00 = (v2f){g0.x,g0.y}, V00 = (v2f){g0.z,g0.w}; \
    const v2f U01 = (v2f){g1.x,g1.y}, V01 = (v2f){g1.z,g1.w}; \
    const v2f U10 = (v2f){g2.x,g2.y}, V10 = (v2f){g2.z,g2.w}; \
    const v2f U11 = (v2f){g3.x,g3.y}, V11 = (v2f){g3.z,g3.w};

#define CBFA(X, Y) { \
    v2f n0 = pk_mul_bl(X, U00); n0 = pk_fma_sw(X, V00, n0); \
    n0 = pk_fma_bl(Y, U01, n0); n0 = pk_fma_sw(Y, V01, n0); \
    v2f n1 = pk_mul_bl(X, U10); n1 = pk_fma_sw(X, V10, n1); \
    n1 = pk_fma_bl(Y, U11, n1); n1 = pk_fma_sw(Y, V11, n1); \
    X = n0; Y = n1; }

#define FE16(M) M(0) M(1) M(2) M(3) M(4) M(5) M(6) M(7) M(8) M(9) M(10) M(11) \
    M(12) M(13) M(14) M(15)

// pair lists by reg-bit stride (16 regs)
#define Q3(M) M(A0,A8) M(A1,A9) M(A2,A10) M(A3,A11) M(A4,A12) M(A5,A13) M(A6,A14) M(A7,A15)
#define Q2(M) M(A0,A4) M(A1,A5) M(A2,A6) M(A3,A7) M(A8,A12) M(A9,A13) M(A10,A14) M(A11,A15)
#define Q1(M) M(A0,A2) M(A1,A3) M(A4,A6) M(A5,A7) M(A8,A10) M(A9,A11) M(A12,A14) M(A13,A15)
#define Q0(M) M(A0,A1) M(A2,A3) M(A4,A5) M(A6,A7) M(A8,A9) M(A10,A11) M(A12,A13) M(A14,A15)

#define UNPACK8Q \
    v2f A0  = (v2f){q0.x,q0.y},  A1  = (v2f){q0.z,q0.w}, \
        A2  = (v2f){q1.x,q1.y},  A3  = (v2f){q1.z,q1.w}, \
        A4  = (v2f){q2.x,q2.y},  A5  = (v2f){q2.z,q2.w}, \
        A6  = (v2f){q3.x,q3.y},  A7  = (v2f){q3.z,q3.w}, \
        A8  = (v2f){q4.x,q4.y},  A9  = (v2f){q4.z,q4.w}, \
        A10 = (v2f){q5.x,q5.y},  A11 = (v2f){q5.z,q5.w}, \
        A12 = (v2f){q6.x,q6.y},  A13 = (v2f){q6.z,q6.w}, \
        A14 = (v2f){q7.x,q7.y},  A15 = (v2f){q7.z,q7.w};

// Stage A: amp = (t<<4)|k, gates wires 13,12,11,10 on k bits 0..3
__device__ __forceinline__ void stageA(float2* st_, const float4* G4, int t)
{
    const int sb = (t << 4) + ((t >> 2) << 1);      // SLOT(t<<4), 16 contiguous
    float4* lp = (float4*)(st_ + sb);
    const float4 q0 = lp[0], q1 = lp[1], q2 = lp[2], q3 = lp[3],
                 q4 = lp[4], q5 = lp[5], q6 = lp[6], q7 = lp[7];
    UNPACK8Q
    { GSTAGE(13) Q0(CBFA) }
    { GSTAGE(12) Q1(CBFA) }
    { GSTAGE(11) Q2(CBFA) }
    { GSTAGE(10) Q3(CBFA) }
    lp[0] = make_float4(A0.x,A0.y,A1.x,A1.y);   lp[1] = make_float4(A2.x,A2.y,A3.x,A3.y);
    lp[2] = make_float4(A4.x,A4.y,A5.x,A5.y);   lp[3] = make_float4(A6.x,A6.y,A7.x,A7.y);
    lp[4] = make_float4(A8.x,A8.y,A9.x,A9.y);   lp[5] = make_float4(A10.x,A10.y,A11.x,A11.y);
    lp[6] = make_float4(A12.x,A12.y,A13.x,A13.y); lp[7] = make_float4(A14.x,A14.y,A15.x,A15.y);
}

// Stage B: amp = (t[9:6]<<10)|(t[5:4]<<8)|(k<<4)|t[3:0]; wires 9..6 on k bits 0..3
__device__ __forceinline__ void stageB(float2* st_, const float4* G4, int t)
{
    const int base = (t & 15) | (((t >> 4) & 3) << 8) | ((t >> 6) << 10);
    float2* p = st_ + (base + ((base >> 6) << 1));
#define OFFB(k) (16*(k) + (((k) >> 2) << 1))
#define LDB(k) v2f A##k = *(const v2f*)(p + OFFB(k));
    FE16(LDB)
#undef LDB
    { GSTAGE(9) Q0(CBFA) }
    { GSTAGE(8) Q1(CBFA) }
    { GSTAGE(7) Q2(CBFA) }
    { GSTAGE(6) Q3(CBFA) }
#define STB(k) *(v2f*)(p + OFFB(k)) = A##k;
    FE16(STB)
#undef STB
#undef OFFB
}

// Stage C: amp = (t[9:6]<<10)|(k98<<8)|(t[5:0]<<2)|k10; reg r = 4*k98+k10.
// Gates: wire 5 on amp bit 8 (r bit 2 -> Q2), wire 4 on amp bit 9 (r bit 3 -> Q3).
__device__ __forceinline__ void stageC(float2* st_, const float4* G4, int t)
{
    const int base = ((t >> 6) << 10) | ((t & 63) << 2);
    float2* p = st_ + (base + ((base >> 6) << 1));   // slotOFF = 264*k98 + k10
    float4* c0 = (float4*)(p);
    float4* c1 = (float4*)(p + 264);
    float4* c2 = (float4*)(p + 528);
    float4* c3 = (float4*)(p + 792);
    const float4 q0 = c0[0], q1 = c0[1], q2 = c1[0], q3 = c1[1],
                 q4 = c2[0], q5 = c2[1], q6 = c3[0], q7 = c3[1];
    UNPACK8Q
    { GSTAGE(5) Q2(CBFA) }
    { GSTAGE(4) Q3(CBFA) }
    c0[0] = make_float4(A0.x,A0.y,A1.x,A1.y);   c0[1] = make_float4(A2.x,A2.y,A3.x,A3.y);
    c1[0] = make_float4(A4.x,A4.y,A5.x,A5.y);   c1[1] = make_float4(A6.x,A6.y,A7.x,A7.y);
    c2[0] = make_float4(A8.x,A8.y,A9.x,A9.y);   c2[1] = make_float4(A10.x,A10.y,A11.x,A11.y);
    c3[0] = make_float4(A12.x,A12.y,A13.x,A13.y); c3[1] = make_float4(A14.x,A14.y,A15.x,A15.y);
}

// Stage D loads/gates: amp = (k<<10)|t; wires 3..0 on k bits 0..3
#define D_LOAD_GATES \
    float2* p = st_ + (t + ((t >> 6) << 1)); \
    v2f A0  = *(const v2f*)(p),            A1  = *(const v2f*)(p + 1056), \
        A2  = *(const v2f*)(p + 2*1056),   A3  = *(const v2f*)(p + 3*1056), \
        A4  = *(const v2f*)(p + 4*1056),   A5  = *(const v2f*)(p + 5*1056), \
        A6  = *(const v2f*)(p + 6*1056),   A7  = *(const v2f*)(p + 7*1056), \
        A8  = *(const v2f*)(p + 8*1056),   A9  = *(const v2f*)(p + 9*1056), \
        A10 = *(const v2f*)(p + 10*1056),  A11 = *(const v2f*)(p + 11*1056), \
        A12 = *(const v2f*)(p + 12*1056),  A13 = *(const v2f*)(p + 13*1056), \
        A14 = *(const v2f*)(p + 14*1056),  A15 = *(const v2f*)(p + 15*1056); \
    { GSTAGE(3) Q0(CBFA) } \
    { GSTAGE(2) Q1(CBFA) } \
    { GSTAGE(1) Q2(CBFA) } \
    { GSTAGE(0) Q3(CBFA) }

// mid-layer D: gates + ring scatter (full XOR + SLOT)
template<int RI>
__device__ __forceinline__ void stageD_ring(float2* st_, const float4* G4, int t,
                                            const unsigned* lA, const unsigned* lB)
{
    D_LOAD_GATES
    const unsigned fb = lA[t & 31] ^ lB[(t >> 5) & 31];
    __syncthreads();                                  // all reads done before scatter
#define SC(k) { const unsigned ix = fb ^ RC.flowD[RI][(k)]; \
    st_[ix + ((ix >> 6) << 1)] = make_float2(A##k.x, A##k.y); }
    FE16(SC)
#undef SC
}

// final D: gates + ring(RI=1) + <Z> measurement, no writeback
__device__ __forceinline__ float stageD_meas(float2* st_, const float4* G4, int t,
                                             const unsigned* lA, const unsigned* lB,
                                             const float* s_hw)
{
    D_LOAD_GATES
    const unsigned fb = lA[t & 31] ^ lB[(t >> 5) & 31];
#define SGV(b) ((((fb >> b) & 1u) ? -1.f : 1.f) * s_hw[13 - (b)])
    const float sg0 = SGV(0),  sg1 = SGV(1),  sg2 = SGV(2),  sg3 = SGV(3),
                sg4 = SGV(4),  sg5 = SGV(5),  sg6 = SGV(6),  sg7 = SGV(7),
                sg8 = SGV(8),  sg9 = SGV(9),  sg10 = SGV(10), sg11 = SGV(11),
                sg12 = SGV(12), sg13 = SGV(13);
#undef SGV
    const float chiS = ((sg0 + sg1) + (sg2 + sg3)) + ((sg4 + sg5) + (sg6 + sg7))
                     + ((sg8 + sg9) + (sg10 + sg11)) + (sg12 + sg13);
#define SUBSUM(F) ( ((F)&1u?sg0:0.f) + ((F)&2u?sg1:0.f) + ((F)&4u?sg2:0.f) + ((F)&8u?sg3:0.f) \
                  + ((F)&16u?sg4:0.f) + ((F)&32u?sg5:0.f) + ((F)&64u?sg6:0.f) + ((F)&128u?sg7:0.f) \
                  + ((F)&256u?sg8:0.f) + ((F)&512u?sg9:0.f) + ((F)&1024u?sg10:0.f) + ((F)&2048u?sg11:0.f) \
                  + ((F)&4096u?sg12:0.f) + ((F)&8192u?sg13:0.f) )
    float acc = 0.f;
#define MEASK(k) { const float p2 = fmaf(A##k.x, A##k.x, A##k.y * A##k.y); \
    acc = fmaf(p2, chiS - 2.f * SUBSUM(RC.flowD[1][(k)]), acc); }
    FE16(MEASK)
#undef MEASK
#undef SUBSUM
    return acc;
}

__global__ __launch_bounds__(NTHREADS, 4)
void qsim(const float* __restrict__ sb, const float* __restrict__ pr,
          const float* __restrict__ hw, const float* __restrict__ hb,
          float* __restrict__ out)
{
    __shared__ __align__(16) float2 st[STATE_SLOTS];   // 135,168 B
    __shared__ __align__(16) float4 rotc[2][NW * 4];   // gate consts (R5 format)
    __shared__ unsigned lutA[2][32], lutB[2][32];      // fb LUTs: amp bits 0..4 / 5..9
    __shared__ float2 tab16[16];                       // layer0 product over wires 3..0
    __shared__ float s_hw[NW];
    __shared__ float s_red[NTHREADS / 64];
    __shared__ unsigned s_bmask;

    const int bid = blockIdx.x;
    const int t = threadIdx.x;

    // ---- setup ----
    if (t < 28) {
        int l = t / NW, w = t % NW;
        const float* p = pr + bid * 84 + l * 42 + w * 3;
        float phi = p[0], th = p[1], om = p[2];
        float s, cth;  __sincosf(0.5f * th, &s, &cth);
        float sa, ca, sd, cd;
        __sincosf(0.5f * (phi + om), &sa, &ca);
        __sincosf(0.5f * (phi - om), &sd, &cd);
        const float u00x = ca * cth, u00y = -sa * cth;
        const float u01x = -cd * s,  u01y = -sd * s;
        const float u10x = cd * s,   u10y = -sd * s;
        const float u11x = ca * cth, u11y = sa * cth;
        rotc[l][w*4+0] = make_float4(u00x, u00y, -u00y, u00y);   // {re, im, -im, +im}
        rotc[l][w*4+1] = make_float4(u01x, u01y, -u01y, u01y);
        rotc[l][w*4+2] = make_float4(u10x, u10y, -u10y, u10y);
        rotc[l][w*4+3] = make_float4(u11x, u11y, -u11y, u11y);
    }
    if (t >= 64 && t < 128) {                   // lutA: amp bits 0..4 -> cols 0..4
        int j = t - 64, ri = j >> 5, m = j & 31;
        unsigned x = 0;
        for (int b = 0; b < 5; ++b) if ((m >> b) & 1) x ^= RC.col[ri][b];
        lutA[ri][m] = x;
    }
    if (t >= 128 && t < 192) {                  // lutB: amp bits 5..9 -> cols 5..9
        int j = t - 128, ri = j >> 5, m = j & 31;
        unsigned x = 0;
        for (int b = 0; b < 5; ++b) if ((m >> b) & 1) x ^= RC.col[ri][5 + b];
        lutB[ri][m] = x;
    }
    if (t >= 192 && t < 206) s_hw[t - 192] = hw[t - 192];
    if (t == 224) {
        const float* row = sb + (size_t)bid * (NSTATE * 2);
        unsigned m = 0;
        for (int w = 0; w < NW; ++w) m |= (row[w] < 0.0f ? 1u : 0u) << (13 - w);
        s_bmask = m;
    }
    __syncthreads();
    if (t < 16) {                               // tab16[k]: amp bits 10..13 = wires 3..0
        const unsigned bm = s_bmask;
        float2 v = make_float2(1.f, 0.f);
#pragma unroll
        for (int j = 0; j < 4; ++j) {
            int w = 3 - j, kb = (t >> j) & 1, cb = (bm >> (10 + j)) & 1;
            float4 e = rotc[0][w*4 + kb*2 + cb];
            v = cmul(v, make_float2(e.x, e.y));
        }
        tab16[t] = v;
    }
    __syncthreads();

    // ---- init: layer 0 on |bm> (product state), ring r=1 folded, D layout ----
    {
        const unsigned bm = s_bmask;
        float2 ph = make_float2(1.f, 0.f);
#pragma unroll
        for (int b = 0; b < 10; ++b) {          // amp bit b = t bit b = wire 13-b
            int w = 13 - b, kb = (t >> b) & 1, cb = (bm >> b) & 1;
            float4 e = rotc[0][w*4 + kb*2 + cb];
            ph = cmul(ph, make_float2(e.x, e.y));
        }
        const unsigned fb = lutA[0][t & 31] ^ lutB[0][(t >> 5) & 31];
#define INITK(k) { const unsigned ix = fb ^ RC.flowD[0][(k)]; \
    st[ix + ((ix >> 6) << 1)] = cmul(ph, tab16[(k)]); }
        FE16(INITK)
#undef INITK
    }
    __syncthreads();

    // ---- layers: (1,0,1,0) mid + final (1). Rings alternate r2,r1,... ----
#pragma unroll 1
    for (int rep = 0; rep < 4; ++rep) {
        const int l = (rep & 1) ? 0 : 1;
        const float4* G4 = &rotc[l][0];
        stageA(st, G4, t); wavewait();
        stageB(st, G4, t); wavewait();
        stageC(st, G4, t);
        __syncthreads();
        if (l) stageD_ring<1>(st, G4, t, lutA[1], lutB[1]);
        else   stageD_ring<0>(st, G4, t, lutA[0], lutB[0]);
        __syncthreads();
    }
    // final: layer 1, ring r=2 + measurement folded
    stageA(st, &rotc[1][0], t); wavewait();
    stageB(st, &rotc[1][0], t); wavewait();
    stageC(st, &rotc[1][0], t);
    __syncthreads();
    float acc = stageD_meas(st, &rotc[1][0], t, lutA[1], lutB[1], s_hw);

    for (int off = 32; off > 0; off >>= 1) acc += __shfl_down(acc, off);
    if ((t & 63) == 0) s_red[t >> 6] = acc;
    __syncthreads();
    if (t == 0) {
        float tot = 0.f;
#pragma unroll
        for (int i = 0; i < NTHREADS / 64; ++i) tot += s_red[i];
        out[bid] = tot + hb[0];
    }
}

extern "C" void kernel_launch(void* const* d_in, const int* in_sizes, int n_in,
                              void* d_out, int out_size, void* d_ws, size_t ws_size,
                              hipStream_t stream)
{
    const float* sb = (const float*)d_in[0];   // state_batch (B, 2^14, 2) f32
    const float* pr = (const float*)d_in[1];   // params (B, 84) f32
    const float* hw = (const float*)d_in[2];   // head_w (1, 14) f32
    const float* hb = (const float*)d_in[3];   // head_b (1,) f32
    float* out = (float*)d_out;                // (B,) f32
    const int B = in_sizes[1] / 84;            // 512
    qsim<<<B, NTHREADS, 0, stream>>>(sb, pr, hw, hb, out);
}